// Round 1
// baseline (153.896 us; speedup 1.0000x reference)
//
#include <hip/hip_runtime.h>
#include <math.h>

#define LEN_M   131328
#define D_H     256
#define N_MC    64
#define D_P1    513
#define NROW    4096

// workspace layout (floats):
//   Wc: [513][512]  combined weights: cols 0..255 = m, 256..511 = sqrt(v)
//   C : [4096][512] GEMM result: cols 0..255 = A, 256..511 = B
#define WC_ELEMS (D_P1 * 2 * D_H)     // 262656
// out layout (floats): pred[4096][64] (262144), m_w0 (131328), v_w0 (131328)
#define PRED_ELEMS (NROW * N_MC)      // 262144

// ---------------------------------------------------------------- prep ------
__global__ __launch_bounds__(256) void prep_kernel(
    const float* __restrict__ params, float* __restrict__ out,
    float* __restrict__ wc)
{
    int i = blockIdx.x * 256 + threadIdx.x;
    if (i >= LEN_M) return;
    float m  = params[i];
    float pv = params[LEN_M + i];
    float v  = fmaxf(pv, 0.0f) + 1e-6f;
    float s  = sqrtf(v);
    out[PRED_ELEMS + i]         = m;   // m_w0 output
    out[PRED_ELEMS + LEN_M + i] = v;   // v_w0 output
    int d = i >> 8;          // / 256
    int h = i & 255;         // % 256
    wc[d * 512 + h]       = m;
    wc[d * 512 + 256 + h] = s;
}

// ---------------------------------------------------------------- gemm ------
// C[4096][512] = x[4096][513] @ Wc[513][512], fp32.
// 64x64 tile, BK=16, 256 threads, 4x4 micro-tile per thread.
__global__ __launch_bounds__(256) void gemm_kernel(
    const float* __restrict__ x, const float* __restrict__ wc,
    float* __restrict__ c)
{
    __shared__ float As[16][68];   // [k][row], pad 68 -> 2-way max on writes
    __shared__ float Bs[16][64];   // [k][col]

    const int bm  = blockIdx.y * 64;
    const int bn  = blockIdx.x * 64;
    const int tid = threadIdx.x;
    const int tx  = tid & 15;      // col group 0..15
    const int ty  = tid >> 4;      // row group 0..15

    // load-index decomposition
    const int a_k = tid & 15;      // k within chunk
    const int a_r = tid >> 4;      // row base 0..15 (4 passes of +16)
    const int b_c = tid & 63;      // col
    const int b_r = tid >> 6;      // k-row base 0..3 (4 passes of +4)

    float acc[4][4] = {};

    for (int k0 = 0; k0 < D_P1; k0 += 16) {
        // stage A: 64 rows x 16 k (guarded on k; K=513 remainder)
        #pragma unroll
        for (int p = 0; p < 4; ++p) {
            int row = a_r + p * 16;
            int gk  = k0 + a_k;
            float va = (gk < D_P1) ? x[(bm + row) * D_P1 + gk] : 0.0f;
            As[a_k][row] = va;
        }
        // stage B: 16 k x 64 cols
        #pragma unroll
        for (int p = 0; p < 4; ++p) {
            int kr = b_r + p * 4;
            int gk = k0 + kr;
            float vb = (gk < D_P1) ? wc[gk * 512 + bn + b_c] : 0.0f;
            Bs[kr][b_c] = vb;
        }
        __syncthreads();

        #pragma unroll
        for (int k = 0; k < 16; ++k) {
            float4 av = *(const float4*)&As[k][ty * 4];
            float4 bv = *(const float4*)&Bs[k][tx * 4];
            float a[4] = {av.x, av.y, av.z, av.w};
            float b[4] = {bv.x, bv.y, bv.z, bv.w};
            #pragma unroll
            for (int i = 0; i < 4; ++i)
                #pragma unroll
                for (int j = 0; j < 4; ++j)
                    acc[i][j] = fmaf(a[i], b[j], acc[i][j]);
        }
        __syncthreads();
    }

    // write C tile, float4 stores (cols consecutive)
    #pragma unroll
    for (int i = 0; i < 4; ++i) {
        int row = bm + ty * 4 + i;
        float4 v0 = make_float4(acc[i][0], acc[i][1], acc[i][2], acc[i][3]);
        *(float4*)&c[row * 512 + bn + tx * 4] = v0;
    }
}

// ---------------------------------------------------------------- pred ------
// pred[n][m] = W1[0] + sum_h relu(A[n][h] + eps[m]*B[n][h]) * W1[h+1]
// One wave per row n; lane = m. 4 rows per block.
__global__ __launch_bounds__(256) void pred_kernel(
    const float* __restrict__ c, const float* __restrict__ W1,
    const float* __restrict__ eps, float* __restrict__ out)
{
    __shared__ float rowbuf[4][512];   // per-wave [A(256) | B(256)]
    __shared__ float w1s[256];         // W1[1..256]

    const int tid  = threadIdx.x;
    const int wave = tid >> 6;
    const int lane = tid & 63;
    const int n    = blockIdx.x * 4 + wave;

    if (tid < 256) w1s[tid] = W1[tid + 1];

    // stage row n: 512 floats, 2 float4 per lane
    const float4* crow = (const float4*)(c + n * 512);
    float4* l4 = (float4*)rowbuf[wave];
    l4[lane]      = crow[lane];
    l4[lane + 64] = crow[lane + 64];
    __syncthreads();

    const float e = eps[lane];
    float acc = W1[0];

    const float4* A4 = (const float4*)rowbuf[wave];          // h 0..255
    const float4* B4 = (const float4*)(rowbuf[wave] + 256);
    const float4* W4 = (const float4*)w1s;

    #pragma unroll 8
    for (int h4 = 0; h4 < 64; ++h4) {
        float4 a = A4[h4];
        float4 b = B4[h4];
        float4 w = W4[h4];
        acc = fmaf(fmaxf(fmaf(e, b.x, a.x), 0.0f), w.x, acc);
        acc = fmaf(fmaxf(fmaf(e, b.y, a.y), 0.0f), w.y, acc);
        acc = fmaf(fmaxf(fmaf(e, b.z, a.z), 0.0f), w.z, acc);
        acc = fmaf(fmaxf(fmaf(e, b.w, a.w), 0.0f), w.w, acc);
    }

    out[n * 64 + lane] = acc;
}

// -------------------------------------------------------------- launch ------
extern "C" void kernel_launch(void* const* d_in, const int* in_sizes, int n_in,
                              void* d_out, int out_size, void* d_ws, size_t ws_size,
                              hipStream_t stream)
{
    const float* params = (const float*)d_in[0];
    const float* W1     = (const float*)d_in[1];
    const float* x      = (const float*)d_in[2];
    const float* eps    = (const float*)d_in[3];
    float* out = (float*)d_out;
    float* wc  = (float*)d_ws;
    float* c   = wc + WC_ELEMS;

    prep_kernel<<<(LEN_M + 255) / 256, 256, 0, stream>>>(params, out, wc);

    dim3 ggrid(512 / 64, NROW / 64);   // (8, 64) = 512 blocks
    gemm_kernel<<<ggrid, 256, 0, stream>>>(x, wc, c);

    pred_kernel<<<NROW / 4, 256, 0, stream>>>(c, W1, eps, out);
}

// Round 2
// 98.904 us; speedup vs baseline: 1.5560x; 1.5560x over previous
//
#include <hip/hip_runtime.h>
#include <hip/hip_bf16.h>
#include <math.h>

#define LEN_M   131328
#define D_H     256
#define N_MC    64
#define D_P1    513
#define NROW    4096
#define KPAD    512
#define PRED_ELEMS (NROW * N_MC)          // 262144

// ws layout:
//   xb   : bf16 [4096][512]   x cast to bf16, col 512 dropped   (4 MB)
//   wcbt : bf16 [512 c][512 k] combined W transposed, k-contig  (512 KB)
//   wcl  : f32  [512]          d=512 row of combined W          (2 KB)
#define XB_ELEMS   (NROW * KPAD)          // 2097152
#define WCBT_ELEMS (512 * 512)

typedef __attribute__((ext_vector_type(8))) short short8;     // 8 bf16 = 4 VGPR
typedef __attribute__((ext_vector_type(4))) float floatx4;    // mfma acc

// ---------------------------------------------------------------- prep_a ----
// i in [0, 4096*512): xb convert; side duties on low indices.
__global__ __launch_bounds__(256) void prep_a(
    const float* __restrict__ params, const float* __restrict__ x,
    float* __restrict__ out, __hip_bfloat16* __restrict__ xb,
    float* __restrict__ wcl)
{
    int i = blockIdx.x * 256 + threadIdx.x;
    int row = i >> 9, col = i & 511;
    xb[i] = __float2bfloat16(x[row * D_P1 + col]);
    if (i < PRED_ELEMS) out[i] = 0.0f;                 // zero pred for atomics
    if (i < LEN_M) {
        float m = params[i];
        float v = fmaxf(params[LEN_M + i], 0.0f) + 1e-6f;
        out[PRED_ELEMS + i]         = m;               // m_w0
        out[PRED_ELEMS + LEN_M + i] = v;               // v_w0
        if (i >= 131072) {                             // d == 512 row
            int h = i - 131072;
            wcl[h]       = m;
            wcl[256 + h] = sqrtf(v);
        }
    }
}

// ---------------------------------------------------------------- prep_b ----
// Build wcbt[c][k] bf16: c<256 -> m(d=k,h=c); c>=256 -> sqrt(v)(d=k,h=c-256).
// 64x64 tile transpose through LDS (coalesced reads, vector writes).
__global__ __launch_bounds__(256) void prep_b(
    const float* __restrict__ params, __hip_bfloat16* __restrict__ wcbt)
{
    __shared__ unsigned short T[64][65];
    const int k0 = blockIdx.x * 64;
    const int c0 = blockIdx.y * 64;
    const int t  = threadIdx.x;
    const int hh = t & 63, kb = t >> 6;
    const bool spart = (c0 >= 256);
    const int hbase = c0 & 255;
    const float* src = params + (spart ? LEN_M : 0);

    #pragma unroll 4
    for (int p = 0; p < 16; ++p) {
        int kk = p * 4 + kb;
        float v = src[(k0 + kk) * 256 + hbase + hh];
        if (spart) v = sqrtf(fmaxf(v, 0.0f) + 1e-6f);
        __hip_bfloat16 b = __float2bfloat16(v);
        T[kk][hh] = *(unsigned short*)&b;
    }
    __syncthreads();

    const int cc = t >> 2, kq = t & 3;
    short8 lo, hi;
    #pragma unroll
    for (int j = 0; j < 8; ++j) lo[j] = (short)T[kq * 16 + j][cc];
    #pragma unroll
    for (int j = 0; j < 8; ++j) hi[j] = (short)T[kq * 16 + 8 + j][cc];
    short* dst = (short*)wcbt + (c0 + cc) * 512 + k0 + kq * 16;
    *(short8*)dst       = lo;
    *(short8*)(dst + 8) = hi;
}

// ------------------------------------------------------------------ main ----
// Grid (4 h-splits, 128 row-tiles). Block: 32 rows x 128 cols (64 A + 64 B).
// Wave w: rows (w&1)*16..+16, colhalf w>>1 (0=A-part, 1=B-part), 4 subtiles.
__global__ __launch_bounds__(256) void main_kernel(
    const __hip_bfloat16* __restrict__ xb, const __hip_bfloat16* __restrict__ wcbt,
    const float* __restrict__ wcl, const float* __restrict__ x,
    const float* __restrict__ W1, const float* __restrict__ eps,
    float* __restrict__ out)
{
    __shared__ float Clds[128 * 36];    // [lcol][row], pad 36 (keeps 16B align)

    const int t = threadIdx.x;
    const int w = t >> 6, lane = t & 63;
    const int lane15 = lane & 15, quad = lane >> 4;
    const int H  = blockIdx.x;          // h-range [H*64, H*64+64)
    const int bm = blockIdx.y * 32;
    const int rowhalf = (w & 1) * 16;
    const int colhalf = w >> 1;

    const int arow  = bm + rowhalf + lane15;
    const int gcol0 = colhalf * 256 + H * 64 + lane15;   // + s*16

    const short* xbs = (const short*)xb;
    const short* wbs = (const short*)wcbt;
    const short* ap  = xbs + arow * 512 + quad * 8;
    const short* bp0 = wbs + (gcol0 +  0) * 512 + quad * 8;
    const short* bp1 = wbs + (gcol0 + 16) * 512 + quad * 8;
    const short* bp2 = wbs + (gcol0 + 32) * 512 + quad * 8;
    const short* bp3 = wbs + (gcol0 + 48) * 512 + quad * 8;

    floatx4 acc0 = {0.f,0.f,0.f,0.f}, acc1 = acc0, acc2 = acc0, acc3 = acc0;

    #pragma unroll 4
    for (int k0 = 0; k0 < 512; k0 += 32) {
        short8 a  = *(const short8*)(ap  + k0);
        short8 b0 = *(const short8*)(bp0 + k0);
        short8 b1 = *(const short8*)(bp1 + k0);
        short8 b2 = *(const short8*)(bp2 + k0);
        short8 b3 = *(const short8*)(bp3 + k0);
        acc0 = __builtin_amdgcn_mfma_f32_16x16x32_bf16(a, b0, acc0, 0, 0, 0);
        acc1 = __builtin_amdgcn_mfma_f32_16x16x32_bf16(a, b1, acc1, 0, 0, 0);
        acc2 = __builtin_amdgcn_mfma_f32_16x16x32_bf16(a, b2, acc2, 0, 0, 0);
        acc3 = __builtin_amdgcn_mfma_f32_16x16x32_bf16(a, b3, acc3, 0, 0, 0);
    }

    // K=513 remainder in fp32, then C -> LDS ([lcol][row] for b128 r/w).
    const int r0 = rowhalf + quad * 4;           // D rows r0..r0+3
    float xl[4];
    #pragma unroll
    for (int r = 0; r < 4; ++r) xl[r] = x[(bm + r0 + r) * D_P1 + 512];

    floatx4 accs[4] = {acc0, acc1, acc2, acc3};
    #pragma unroll
    for (int s = 0; s < 4; ++s) {
        const int gcol = gcol0 + s * 16;
        const float wl = wcl[gcol];
        float4 vv;
        vv.x = accs[s][0] + xl[0] * wl;
        vv.y = accs[s][1] + xl[1] * wl;
        vv.z = accs[s][2] + xl[2] * wl;
        vv.w = accs[s][3] + xl[3] * wl;
        const int lcol = colhalf * 64 + s * 16 + lane15;   // [0,128)
        *(float4*)&Clds[lcol * 36 + r0] = vv;
    }
    __syncthreads();

    // pred epilogue: lane = m, wave handles 8 local rows; broadcast LDS reads.
    const float e = eps[lane];
    const int rb = w * 8;
    float accp[8];
    const float init = (H == 0) ? W1[0] : 0.0f;
    #pragma unroll
    for (int r = 0; r < 8; ++r) accp[r] = init;

    #pragma unroll 4
    for (int hl = 0; hl < 64; ++hl) {
        const float w1h = W1[1 + H * 64 + hl];
        const float4 a0 = *(const float4*)&Clds[hl * 36 + rb];
        const float4 a1 = *(const float4*)&Clds[hl * 36 + rb + 4];
        const float4 b0 = *(const float4*)&Clds[(64 + hl) * 36 + rb];
        const float4 b1 = *(const float4*)&Clds[(64 + hl) * 36 + rb + 4];
        accp[0] = fmaf(fmaxf(fmaf(e, b0.x, a0.x), 0.f), w1h, accp[0]);
        accp[1] = fmaf(fmaxf(fmaf(e, b0.y, a0.y), 0.f), w1h, accp[1]);
        accp[2] = fmaf(fmaxf(fmaf(e, b0.z, a0.z), 0.f), w1h, accp[2]);
        accp[3] = fmaf(fmaxf(fmaf(e, b0.w, a0.w), 0.f), w1h, accp[3]);
        accp[4] = fmaf(fmaxf(fmaf(e, b1.x, a1.x), 0.f), w1h, accp[4]);
        accp[5] = fmaf(fmaxf(fmaf(e, b1.y, a1.y), 0.f), w1h, accp[5]);
        accp[6] = fmaf(fmaxf(fmaf(e, b1.z, a1.z), 0.f), w1h, accp[6]);
        accp[7] = fmaf(fmaxf(fmaf(e, b1.w, a1.w), 0.f), w1h, accp[7]);
    }

    float* op = out + (bm + rb) * 64 + lane;
    #pragma unroll
    for (int r = 0; r < 8; ++r)
        unsafeAtomicAdd(op + r * 64, accp[r]);
}

// -------------------------------------------------------------- launch ------
extern "C" void kernel_launch(void* const* d_in, const int* in_sizes, int n_in,
                              void* d_out, int out_size, void* d_ws, size_t ws_size,
                              hipStream_t stream)
{
    const float* params = (const float*)d_in[0];
    const float* W1     = (const float*)d_in[1];
    const float* x      = (const float*)d_in[2];
    const float* eps    = (const float*)d_in[3];
    float* out = (float*)d_out;

    __hip_bfloat16* xb   = (__hip_bfloat16*)d_ws;
    __hip_bfloat16* wcbt = xb + XB_ELEMS;
    float*          wcl  = (float*)(wcbt + WCBT_ELEMS);

    prep_a<<<XB_ELEMS / 256, 256, 0, stream>>>(params, x, out, xb, wcl);
    prep_b<<<dim3(8, 8), 256, 0, stream>>>(params, wcbt);
    main_kernel<<<dim3(4, 128), 256, 0, stream>>>(xb, wcbt, wcl, x, W1, eps, out);
}